// Round 4
// baseline (1421.647 us; speedup 1.0000x reference)
//
#include <hip/hip_runtime.h>
#include <hip/hip_bf16.h>

// ============================ DIAGNOSTIC ROUND =============================
// Kernels are the round-0 best config (node v1 + edge v2), but each loops
// `rep` times internally (node 10x, edge 5x). Purpose: push each dispatch
// above the ~194 us poison-fill duration so both appear in rocprof top-5
// WITH counters, resolving (a) per-kernel duration n, e; (b) how many fills
// the timed graph contains: dur = k*193.5 + 10n + 5e.
// Both kernels are pure functions of their inputs -> internal repetition is
// idempotent and bitwise-identical output. A per-iteration asm memory
// barrier stops cross-iteration load hoisting/CSE.
// ===========================================================================

#define F 128
#define TM 32
#define NEG_SLOPE 0.01f

typedef float vfloat4 __attribute__((ext_vector_type(4)));

// ---------------------------------------------------------------------------
// Kernel A (v1, round-0 config): Y = src_h @ W + b, fused yz/ss epilogue.
// ---------------------------------------------------------------------------
__global__ __launch_bounds__(256) void node_kernel(
    const float* __restrict__ src_h,   // [N,128]
    const float* __restrict__ self_h,  // [N,128]
    const float* __restrict__ W,       // [128,128]
    const float* __restrict__ b,       // [128]
    const float* __restrict__ attn_W,  // [256]
    float* __restrict__ Y,             // [N,128] (ws)
    float* __restrict__ yz,            // [N]     (ws)
    float* __restrict__ ss,            // [N]     (ws)
    int N, int rep)
{
    __shared__ float Wl[F * F];        // 64 KB
    __shared__ float Al[TM * F];       // 16 KB

    const int t = threadIdx.x;
    const int row0 = blockIdx.x * TM;

    for (int r_ = 0; r_ < rep; ++r_) {
        asm volatile("" ::: "memory");   // keep every load/store per iteration

        // Stage W into LDS: 16384 floats, 256 threads x 16 float4
        for (int i = t * 4; i < F * F; i += 256 * 4) {
            *(float4*)&Wl[i] = *(const float4*)&W[i];
        }
        // Stage A tile (TM x 128)
        for (int i = t; i < TM * F / 4; i += 256) {
            const int r  = i >> 5;
            const int c4 = i & 31;
            const int gr = row0 + r;
            float4 v = make_float4(0.f, 0.f, 0.f, 0.f);
            if (gr < N) v = *(const float4*)&src_h[(size_t)gr * F + c4 * 4];
            *(float4*)&Al[r * F + c4 * 4] = v;
        }
        __syncthreads();

        const int colgrp = t & 31;
        const int rowgrp = t >> 5;
        const int c0 = colgrp * 4;
        const int r0 = rowgrp * 4;

        float acc[4][4] = {};

        #pragma unroll 4
        for (int k = 0; k < F; k += 4) {
            const float4 w0 = *(const float4*)&Wl[(k + 0) * F + c0];
            const float4 w1 = *(const float4*)&Wl[(k + 1) * F + c0];
            const float4 w2 = *(const float4*)&Wl[(k + 2) * F + c0];
            const float4 w3 = *(const float4*)&Wl[(k + 3) * F + c0];
            #pragma unroll
            for (int i = 0; i < 4; i++) {
                const float4 a = *(const float4*)&Al[(r0 + i) * F + k];
                acc[i][0] += a.x * w0.x + a.y * w1.x + a.z * w2.x + a.w * w3.x;
                acc[i][1] += a.x * w0.y + a.y * w1.y + a.z * w2.y + a.w * w3.y;
                acc[i][2] += a.x * w0.z + a.y * w1.z + a.z * w2.z + a.w * w3.z;
                acc[i][3] += a.x * w0.w + a.y * w1.w + a.z * w2.w + a.w * w3.w;
            }
        }

        const float4 bb  = *(const float4*)&b[c0];
        const float4 waz = *(const float4*)&attn_W[c0];
        const float4 was = *(const float4*)&attn_W[F + c0];

        #pragma unroll
        for (int i = 0; i < 4; i++) {
            const int gr = row0 + r0 + i;
            float4 o;
            o.x = acc[i][0] + bb.x;
            o.y = acc[i][1] + bb.y;
            o.z = acc[i][2] + bb.z;
            o.w = acc[i][3] + bb.w;

            float pz = o.x * waz.x + o.y * waz.y + o.z * waz.z + o.w * waz.w;

            float ps = 0.f;
            if (gr < N) {
                const float4 s = *(const float4*)&self_h[(size_t)gr * F + c0];
                ps = s.x * was.x + s.y * was.y + s.z * was.z + s.w * was.w;
            }

            #pragma unroll
            for (int m = 16; m >= 1; m >>= 1) {
                pz += __shfl_xor(pz, m, 32);
                ps += __shfl_xor(ps, m, 32);
            }

            if (gr < N) {
                *(float4*)&Y[(size_t)gr * F + c0] = o;
                if (colgrp == 0) {
                    yz[gr] = pz;
                    ss[gr] = ps;
                }
            }
        }
        __syncthreads();   // protect LDS before next repetition re-stages
    }
}

// ---------------------------------------------------------------------------
// Kernel B (v2, round-0 config): per-edge gather + logit, NT z1 stores.
// ---------------------------------------------------------------------------
#define EDGE_BLOCKS 2048

__global__ __launch_bounds__(256) void edge_kernel(
    const int* __restrict__ src_idx,
    const int* __restrict__ dst_idx,
    const float* __restrict__ Y,
    const float* __restrict__ yz,
    const float* __restrict__ ss,
    const float* __restrict__ attn_b,
    float* __restrict__ z1,            // [E,128]
    float* __restrict__ e_out,         // [E]
    int E, int rep)
{
    const int lane = threadIdx.x & 31;
    const int g    = blockIdx.x * 8 + (threadIdx.x >> 5);
    const int nG   = EDGE_BLOCKS * 8;
    const float ab = attn_b[0];

    for (int r_ = 0; r_ < rep; ++r_) {
        asm volatile("" ::: "memory");   // keep every load/store per iteration

        for (int e = g; e < E; e += nG) {
            const int s = src_idx[e];
            const vfloat4 v = *(const vfloat4*)&Y[(size_t)s * F + lane * 4];
            __builtin_nontemporal_store(v, (vfloat4*)&z1[(size_t)e * F + lane * 4]);

            if (lane == 0) {
                const int d = dst_idx[e];
                const float a = yz[s] + ss[d] + ab;
                __builtin_nontemporal_store((a >= 0.f) ? a : NEG_SLOPE * a,
                                            &e_out[e]);
            }
        }
    }
}

extern "C" void kernel_launch(void* const* d_in, const int* in_sizes, int n_in,
                              void* d_out, int out_size, void* d_ws, size_t ws_size,
                              hipStream_t stream)
{
    const float* src_h  = (const float*)d_in[0];
    const float* self_h = (const float*)d_in[1];
    const int*   src_idx = (const int*)d_in[2];
    const int*   dst_idx = (const int*)d_in[3];
    const float* W      = (const float*)d_in[4];
    const float* b      = (const float*)d_in[5];
    const float* attn_W = (const float*)d_in[6];
    const float* attn_b = (const float*)d_in[7];

    const int N = in_sizes[0] / F;     // 50000
    const int E = in_sizes[2];         // 600000

    float* z1    = (float*)d_out;                      // [E,128]
    float* e_out = (float*)d_out + (size_t)E * F;      // [E]

    float* Y  = (float*)d_ws;                          // [N,128]
    float* yz = Y + (size_t)N * F;                     // [N]
    float* ss = yz + N;                                // [N]

    // DIAGNOSTIC: node x10, edge x5 (internal reps) so both dispatches
    // exceed the ~194 us fill and surface in rocprof top-5 with counters.
    node_kernel<<<dim3((N + TM - 1) / TM), 256, 0, stream>>>(
        src_h, self_h, W, b, attn_W, Y, yz, ss, N, 10);

    edge_kernel<<<dim3(EDGE_BLOCKS), 256, 0, stream>>>(
        src_idx, dst_idx, Y, yz, ss, attn_b, z1, e_out, E, 5);
}

// Round 5
// 436.439 us; speedup vs baseline: 3.2574x; 3.2574x over previous
//
#include <hip/hip_runtime.h>
#include <hip/hip_bf16.h>

// Problem constants (shapes from reference): in_f = out_f = 128.
#define F 128
#define TM 32            // rows per block in node GEMM
#define KC 32            // k-rows of W staged per chunk (16 KB)
#define NEG_SLOPE 0.01f

typedef float vfloat4 __attribute__((ext_vector_type(4)));

// ---------------------------------------------------------------------------
// Kernel A v3: per-node GEMM  Y = src_h @ W + b, fused yz/ss epilogue.
//
// R3 diagnostic found: node = 73 us vs 31 us LDS-pipe floor; VGPR=136 and
// LDS=80KB both capped occupancy at 2 waves/SIMD; lock-stepped waves left
// the LDS pipe 42% utilized. R2's chunking failed because launch_bounds
// min-waves forced VGPR 152->128 with spills.
//
// This version targets 4 waves/SIMD with NO spills:
//  - W staged in 4 x 16 KB chunks -> LDS 32 KB/block (5 blocks LDS-wise).
//  - Staging via __builtin_amdgcn_global_load_lds width=16: async direct
//    global->LDS, zero staging VGPRs (linear dest = wave base + lane*16,
//    which our layout matches exactly).
//  - #pragma unroll 2 on the k-loop: 8 in-flight ds_read_b128 (32 VGPR)
//    instead of 32 (128 VGPR).
// Target ~90 VGPR -> 4 waves/SIMD, 4 blocks/CU, desynced barriers.
// ---------------------------------------------------------------------------
__global__ __launch_bounds__(256) void node_kernel(
    const float* __restrict__ src_h,   // [N,128]
    const float* __restrict__ self_h,  // [N,128]
    const float* __restrict__ W,       // [128,128]
    const float* __restrict__ b,       // [128]
    const float* __restrict__ attn_W,  // [256]
    float* __restrict__ Y,             // [N,128] (ws)
    float* __restrict__ yz,            // [N]     (ws)
    float* __restrict__ ss,            // [N]     (ws)
    int N)
{
    __shared__ float Wl[KC * F];       // 16 KB
    __shared__ float Al[TM * F];       // 16 KB

    const int t    = threadIdx.x;
    const int lane = t & 63;           // lane in wave
    const int w    = t >> 6;           // wave 0..3
    const int row0 = blockIdx.x * TM;

    // ---- Stage A tile (TM x 128 = 16 KB, contiguous rows in global) ----
    if (row0 + TM <= N) {
        // 16 async 1 KB transfers: wave w covers quarters w*4..w*4+3.
        #pragma unroll
        for (int j = 0; j < 4; ++j) {
            const int m = w * 4 + j;                  // 0..15
            __builtin_amdgcn_global_load_lds(
                (const __attribute__((address_space(1))) void*)
                    &src_h[(size_t)row0 * F + m * 256 + lane * 4],
                (__attribute__((address_space(3))) void*)&Al[m * 256],
                16, 0, 0);
        }
    } else {
        // tail block: guarded loads, zero-fill OOB rows
        for (int i = t; i < TM * F / 4; i += 256) {
            const int r  = i >> 5;
            const int c4 = i & 31;
            const int gr = row0 + r;
            float4 v = make_float4(0.f, 0.f, 0.f, 0.f);
            if (gr < N) v = *(const float4*)&src_h[(size_t)gr * F + c4 * 4];
            *(float4*)&Al[r * F + c4 * 4] = v;
        }
    }

    // ---- Stage W chunk 0 (KC x 128 = 16 KB) ----
    #pragma unroll
    for (int j = 0; j < 4; ++j) {
        const int m = w * 4 + j;
        __builtin_amdgcn_global_load_lds(
            (const __attribute__((address_space(1))) void*)
                &W[m * 256 + lane * 4],
            (__attribute__((address_space(3))) void*)&Wl[m * 256],
            16, 0, 0);
    }
    __syncthreads();   // compiler drains vmcnt(0) before s_barrier

    const int colgrp = t & 31;
    const int rowgrp = t >> 5;
    const int c0 = colgrp * 4;
    const int r0 = rowgrp * 4;

    float acc[4][4] = {};

    for (int c = 0; ; ++c) {
        const int kbase = c * KC;

        #pragma unroll 2
        for (int k = 0; k < KC; k += 4) {
            const float4 w0 = *(const float4*)&Wl[(k + 0) * F + c0];
            const float4 w1 = *(const float4*)&Wl[(k + 1) * F + c0];
            const float4 w2 = *(const float4*)&Wl[(k + 2) * F + c0];
            const float4 w3 = *(const float4*)&Wl[(k + 3) * F + c0];
            #pragma unroll
            for (int i = 0; i < 4; i++) {
                const float4 a = *(const float4*)&Al[(r0 + i) * F + kbase + k];
                acc[i][0] += a.x * w0.x + a.y * w1.x + a.z * w2.x + a.w * w3.x;
                acc[i][1] += a.x * w0.y + a.y * w1.y + a.z * w2.y + a.w * w3.y;
                acc[i][2] += a.x * w0.z + a.y * w1.z + a.z * w2.z + a.w * w3.z;
                acc[i][3] += a.x * w0.w + a.y * w1.w + a.z * w2.w + a.w * w3.w;
            }
        }

        if (c == F / KC - 1) break;

        __syncthreads();               // all reads of Wl chunk c done
        #pragma unroll
        for (int j = 0; j < 4; ++j) {
            const int m = w * 4 + j;
            __builtin_amdgcn_global_load_lds(
                (const __attribute__((address_space(1))) void*)
                    &W[(size_t)(c + 1) * KC * F + m * 256 + lane * 4],
                (__attribute__((address_space(3))) void*)&Wl[m * 256],
                16, 0, 0);
        }
        __syncthreads();               // vmcnt drained -> chunk c+1 visible
    }

    // ---- Epilogue: bias, store Y, reduce yz and ss ----
    const float4 bb  = *(const float4*)&b[c0];
    const float4 waz = *(const float4*)&attn_W[c0];        // Wa_z slice
    const float4 was = *(const float4*)&attn_W[F + c0];    // Wa_s slice

    #pragma unroll
    for (int i = 0; i < 4; i++) {
        const int gr = row0 + r0 + i;
        float4 o;
        o.x = acc[i][0] + bb.x;
        o.y = acc[i][1] + bb.y;
        o.z = acc[i][2] + bb.z;
        o.w = acc[i][3] + bb.w;

        float pz = o.x * waz.x + o.y * waz.y + o.z * waz.z + o.w * waz.w;

        float ps = 0.f;
        if (gr < N) {
            const float4 s = *(const float4*)&self_h[(size_t)gr * F + c0];
            ps = s.x * was.x + s.y * was.y + s.z * was.z + s.w * was.w;
        }

        #pragma unroll
        for (int m = 16; m >= 1; m >>= 1) {
            pz += __shfl_xor(pz, m, 32);
            ps += __shfl_xor(ps, m, 32);
        }

        if (gr < N) {
            *(float4*)&Y[(size_t)gr * F + c0] = o;
            if (colgrp == 0) {
                yz[gr] = pz;
                ss[gr] = ps;
            }
        }
    }
}

// ---------------------------------------------------------------------------
// Kernel B v2 (control, measured 72 us ~ 1.3x its 52 us NT-write floor):
// per-edge gather + logit, grid-stride, NT z1 row stores.
// ---------------------------------------------------------------------------
#define EDGE_BLOCKS 2048

__global__ __launch_bounds__(256) void edge_kernel(
    const int* __restrict__ src_idx,
    const int* __restrict__ dst_idx,
    const float* __restrict__ Y,
    const float* __restrict__ yz,
    const float* __restrict__ ss,
    const float* __restrict__ attn_b,
    float* __restrict__ z1,            // [E,128]
    float* __restrict__ e_out,         // [E]
    int E)
{
    const int lane = threadIdx.x & 31;
    const int g    = blockIdx.x * 8 + (threadIdx.x >> 5);
    const int nG   = EDGE_BLOCKS * 8;
    const float ab = attn_b[0];

    for (int e = g; e < E; e += nG) {
        const int s = src_idx[e];
        const vfloat4 v = *(const vfloat4*)&Y[(size_t)s * F + lane * 4];
        __builtin_nontemporal_store(v, (vfloat4*)&z1[(size_t)e * F + lane * 4]);

        if (lane == 0) {
            const int d = dst_idx[e];
            const float a = yz[s] + ss[d] + ab;
            __builtin_nontemporal_store((a >= 0.f) ? a : NEG_SLOPE * a,
                                        &e_out[e]);
        }
    }
}

extern "C" void kernel_launch(void* const* d_in, const int* in_sizes, int n_in,
                              void* d_out, int out_size, void* d_ws, size_t ws_size,
                              hipStream_t stream)
{
    const float* src_h  = (const float*)d_in[0];
    const float* self_h = (const float*)d_in[1];
    const int*   src_idx = (const int*)d_in[2];
    const int*   dst_idx = (const int*)d_in[3];
    const float* W      = (const float*)d_in[4];
    const float* b      = (const float*)d_in[5];
    const float* attn_W = (const float*)d_in[6];
    const float* attn_b = (const float*)d_in[7];

    const int N = in_sizes[0] / F;     // 50000
    const int E = in_sizes[2];         // 600000

    float* z1    = (float*)d_out;                      // [E,128]
    float* e_out = (float*)d_out + (size_t)E * F;      // [E]

    float* Y  = (float*)d_ws;                          // [N,128]
    float* yz = Y + (size_t)N * F;                     // [N]
    float* ss = yz + N;                                // [N]

    node_kernel<<<dim3((N + TM - 1) / TM), 256, 0, stream>>>(
        src_h, self_h, W, b, attn_W, Y, yz, ss, N);

    edge_kernel<<<dim3(EDGE_BLOCKS), 256, 0, stream>>>(
        src_idx, dst_idx, Y, yz, ss, attn_b, z1, e_out, E);
}